// Round 6
// baseline (4646.136 us; speedup 1.0000x reference)
//
#include <hip/hip_runtime.h>
#include <math.h>

#define BB 512   // batch
#define TT 2048  // timesteps
#define DD 64    // input dim
#define HH 66    // hidden
#define GG 264   // 4*HH gates
#define GP 272   // padded gates (17 mfma n-tiles of 16), tr row stride
#define NTILE 17
#define NSUB 128 // 128 subchunks x 16 steps = 2048

typedef __attribute__((ext_vector_type(8))) __bf16 bf8_t;
typedef __attribute__((ext_vector_type(8))) unsigned short us8_t;
typedef __attribute__((ext_vector_type(4))) float f4_t;

__device__ __forceinline__ float fast_sigmoid(float x) {
  float e = __expf(-x);
  return __fdividef(1.0f, 1.0f + e);
}
__device__ __forceinline__ float fast_tanh(float x) {
  float e = __expf(2.0f * x);
  return 1.0f - __fdividef(2.0f, e + 1.0f);
}
__device__ __forceinline__ unsigned short f2bf(float f) {
  unsigned u = __builtin_bit_cast(unsigned, f);
  unsigned r = (u + 0x7fffu + ((u >> 16) & 1u)) >> 16;
  return (unsigned short)r;
}
__device__ __forceinline__ float bf2f(unsigned short h) {
  unsigned u = ((unsigned)h) << 16;
  return __builtin_bit_cast(float, u);
}
static __device__ __forceinline__ bf8_t as_bf8(us8_t u) {
  union { us8_t u; bf8_t b; } v; v.u = u; return v.b;
}
__device__ __forceinline__ void pack_hilo(float4 p0, float4 p1, us8_t& hi, us8_t& lo) {
  float v[8] = {p0.x, p0.y, p0.z, p0.w, p1.x, p1.y, p1.z, p1.w};
#pragma unroll
  for (int i = 0; i < 8; ++i) {
    unsigned short h = f2bf(v[i]);
    hi[i] = h;
    lo[i] = f2bf(v[i] - bf2f(h));
  }
}

// R9 (2-wave gate-split): R5's one-wave design needed 330+ named weights ->
// VGPR_Count hit the 256 ArchVGPR cap and spilled to scratch (FETCH +85MB,
// WRITE +50MB). Split gate types across 2 waves: wave 0 holds rows i,g of
// cell l in lane l; wave 1 holds f,o. 132 named weights/lane fits.
#define L66(X) \
  X(0) X(1) X(2) X(3) X(4) X(5) X(6) X(7) X(8) X(9) \
  X(10) X(11) X(12) X(13) X(14) X(15) X(16) X(17) X(18) X(19) \
  X(20) X(21) X(22) X(23) X(24) X(25) X(26) X(27) X(28) X(29) \
  X(30) X(31) X(32) X(33) X(34) X(35) X(36) X(37) X(38) X(39) \
  X(40) X(41) X(42) X(43) X(44) X(45) X(46) X(47) X(48) X(49) \
  X(50) X(51) X(52) X(53) X(54) X(55) X(56) X(57) X(58) X(59) \
  X(60) X(61) X(62) X(63) X(64) X(65)

#define L16A(X) X(0) X(1) X(2) X(3) X(4) X(5) X(6) X(7) X(8) X(9) X(10) X(11) X(12) X(13) X(14) X(15)
#define L16B(X) X(16) X(17) X(18) X(19) X(20) X(21) X(22) X(23) X(24) X(25) X(26) X(27) X(28) X(29) X(30) X(31)
#define L16C(X) X(32) X(33) X(34) X(35) X(36) X(37) X(38) X(39) X(40) X(41) X(42) X(43) X(44) X(45) X(46) X(47)
#define L16D(X) X(48) X(49) X(50) X(51) X(52) X(53) X(54) X(55) X(56) X(57) X(58) X(59) X(60) X(61) X(62) X(63)

#define DECLW(i) float u##i, v##i;
#define LOADW(i) u##i = pu[(i)]; v##i = pv[(i)];

// Batched readlanes (R2/R4 lesson: 16 rdl THEN the fmas — first fma reads an
// SGPR written 16 instrs earlier, no VALU->SGPR->VALU wait states). h_ is
// lane-resident in BOTH waves (redundant cell update), so rdl needs no LDS.
#define RDLH(i) const float hk##i = __builtin_bit_cast(float, __builtin_amdgcn_readlane(hsrc, (i)));
#define FM2(i) accU = fmaf(hk##i, u##i, accU); accV = fmaf(hk##i, v##i, accV);

// Kernel 0: W_ih fp32 -> bf16 hi/lo, PERMUTED to cell-major row order
// r' = 4*cell + type (<- src row type*66+cell), padded to 272 rows.
// Leftover rows land at r' = 256..263 = (cell 64|65, type 0..3).
__global__ void conv_w(const float* __restrict__ W_ih,
                       unsigned short* __restrict__ hi,
                       unsigned short* __restrict__ lo) {
  int i = blockIdx.x * 256 + threadIdx.x;
  if (i >= GP * DD) return;
  int n = i >> 6, d = i & 63;
  float w = 0.0f;
  if (n < GG) {
    int c = n >> 2, t = n & 3;
    w = W_ih[(t * HH + c) * DD + d];
  }
  unsigned short h = f2bf(w);
  hi[i] = h;
  lo[i] = f2bf(w - bf2f(h));
}

// R9: TWO waves per sequence (gate-type split). Per step:
//  - each wave: 64 batched rdl + 132 fma -> its 2 preacts per cell
//  - cells 64/65: per-lane h_*w + 6-level shfl_xor butterfly (4 regs)
//  - ONE barrier: waves swap preact pairs (8 B/lane, parity double-buffered)
//  - BOTH waves redundantly run the cell update (R6 trick) -> h_ lane-
//    resident in both waves, h64/h65 wave-uniform; zero h exchange.
// Grid 512 x 128 = 1024 waves = 4/CU (one per SIMD). ~210 peak VGPR.
__global__ __launch_bounds__(128, 1) void lstm_two(
    const float* __restrict__ x,      // [B,T,D]
    const float* __restrict__ W_hh,   // [264,66] type-major rows
    const float* __restrict__ b_ih,   // [264]
    const float* __restrict__ b_hh,   // [264]
    const unsigned short* __restrict__ WbHi,  // [272,64] bf16, cell-major rows
    const unsigned short* __restrict__ WbLo,  // [272,64] bf16
    float* __restrict__ hT)           // [66,512]
{
  __shared__ __align__(16) float tr[16 * GP];      // x_proj tile (17408 B)
  __shared__ __align__(16) float sMa[2][2][66];    // [parity][wave][cell] preact U
  __shared__ __align__(16) float sMb[2][2][66];    // [parity][wave][cell] preact V
  __shared__ __align__(16) float sX[2][2][4];      // [parity][wave] leftover preacts

  const int b = blockIdx.x;
  const int tid = threadIdx.x;
  const int wv = tid >> 6;   // 0: holds i,g rows; 1: holds f,o rows
  const int l = tid & 63;    // lane == cell index (cells 0..63)
  const int mlane = l & 15;
  const int quad = l >> 4;

  const int tA = wv ? 1 : 0;  // gate type of row u (i or f)
  const int tB = wv ? 3 : 2;  // gate type of row v (g or o)

  // 132 named weight scalars: rows (tA,cell l) and (tB,cell l).
  L66(DECLW)
  {
    const float* pu = W_hh + (tA * HH + l) * HH;
    const float* pv = W_hh + (tB * HH + l) * HH;
    L66(LOADW)
  }
  // Leftover rows: cells 64,65 x this wave's two types. Col l per lane (4
  // regs) + cols 64,65 uniform (8 regs) + biases (4 regs).
  const int lr0 = tA * HH + 64, lr1 = tA * HH + 65;
  const int lr2 = tB * HH + 64, lr3 = tB * HH + 65;
  const float xc0 = W_hh[lr0 * HH + l], xc1 = W_hh[lr1 * HH + l];
  const float xc2 = W_hh[lr2 * HH + l], xc3 = W_hh[lr3 * HH + l];
  const float xka0 = W_hh[lr0 * HH + 64], xkb0 = W_hh[lr0 * HH + 65];
  const float xka1 = W_hh[lr1 * HH + 64], xkb1 = W_hh[lr1 * HH + 65];
  const float xka2 = W_hh[lr2 * HH + 64], xkb2 = W_hh[lr2 * HH + 65];
  const float xka3 = W_hh[lr3 * HH + 64], xkb3 = W_hh[lr3 * HH + 65];
  const float bx0 = b_ih[lr0] + b_hh[lr0];
  const float bx1 = b_ih[lr1] + b_hh[lr1];
  const float bx2 = b_ih[lr2] + b_hh[lr2];
  const float bx3 = b_ih[lr3] + b_hh[lr3];
  const float biasU = b_ih[tA * HH + l] + b_hh[tA * HH + l];
  const float biasV = b_ih[tB * HH + l] + b_hh[tB * HH + l];

  float c_ = 0.0f, h_ = 0.0f;
  float c64 = 0.0f, c65 = 0.0f, h64v = 0.0f, h65v = 0.0f;

  for (int sc = 0; sc < NSUB; ++sc) {
    // ---- x-projection (bf16 hi/lo MFMA), tiles split by wave parity ----
    {
      const float* src = x + ((size_t)b * TT + sc * 16 + mlane) * DD;
      float4 a00 = *(const float4*)(src + quad * 8);
      float4 a01 = *(const float4*)(src + quad * 8 + 4);
      float4 a10 = *(const float4*)(src + 32 + quad * 8);
      float4 a11 = *(const float4*)(src + 32 + quad * 8 + 4);
      us8_t ah0, al0, ah1, al1;
      pack_hilo(a00, a01, ah0, al0);
      pack_hilo(a10, a11, ah1, al1);
#pragma unroll 2
      for (int ti = wv; ti < NTILE; ti += 2) {
        int n = ti * 16 + mlane;
        const us8_t* bh = (const us8_t*)(WbHi + n * DD + quad * 8);
        const us8_t* bl = (const us8_t*)(WbLo + n * DD + quad * 8);
        us8_t bh0 = bh[0], bh1 = bh[4];
        us8_t bl0 = bl[0], bl1 = bl[4];
        f4_t acc = {0.0f, 0.0f, 0.0f, 0.0f};
        acc = __builtin_amdgcn_mfma_f32_16x16x32_bf16(as_bf8(ah0), as_bf8(bh0), acc, 0, 0, 0);
        acc = __builtin_amdgcn_mfma_f32_16x16x32_bf16(as_bf8(ah1), as_bf8(bh1), acc, 0, 0, 0);
        acc = __builtin_amdgcn_mfma_f32_16x16x32_bf16(as_bf8(al0), as_bf8(bh0), acc, 0, 0, 0);
        acc = __builtin_amdgcn_mfma_f32_16x16x32_bf16(as_bf8(al1), as_bf8(bh1), acc, 0, 0, 0);
        acc = __builtin_amdgcn_mfma_f32_16x16x32_bf16(as_bf8(ah0), as_bf8(bl0), acc, 0, 0, 0);
        acc = __builtin_amdgcn_mfma_f32_16x16x32_bf16(as_bf8(ah1), as_bf8(bl1), acc, 0, 0, 0);
#pragma unroll
        for (int r = 0; r < 4; ++r) tr[(quad * 4 + r) * GP + n] = acc[r];
      }
    }
    __syncthreads();  // tr ready (both waves' tiles)

    for (int s = 0; s < 16; ++s) {
      const int par = s & 1;
      // Leftover-cell dot: per-lane product with OWN h_, then butterfly.
      // Issued first so the ~6-level LDS-swizzle chain hides under the fmas.
      float pr0 = h_ * xc0, pr1 = h_ * xc1, pr2 = h_ * xc2, pr3 = h_ * xc3;
#pragma unroll
      for (int m = 1; m < 64; m <<= 1) {
        pr0 += __shfl_xor(pr0, m);
        pr1 += __shfl_xor(pr1, m);
        pr2 += __shfl_xor(pr2, m);
        pr3 += __shfl_xor(pr3, m);
      }
      float4 p4 = *(const float4*)&tr[s * GP + 4 * l];   // xproj i,f,g,o of cell l
      float4 xq0 = *(const float4*)&tr[s * GP + 256];    // xproj cell64 (uniform)
      float4 xq1 = *(const float4*)&tr[s * GP + 260];    // xproj cell65 (uniform)
      float accU = (wv ? p4.y : p4.x) + biasU;
      float accV = (wv ? p4.w : p4.z) + biasV;
      const int hsrc = __builtin_bit_cast(int, h_);
      { L16A(RDLH) L16A(FM2) }
      { L16B(RDLH) L16B(FM2) }
      { L16C(RDLH) L16C(FM2) }
      { L16D(RDLH) L16D(FM2) }
      accU = fmaf(h64v, u64, accU); accU = fmaf(h65v, u65, accU);
      accV = fmaf(h64v, v64, accV); accV = fmaf(h65v, v65, accV);
      float pX0 = pr0 + fmaf(h64v, xka0, fmaf(h65v, xkb0, bx0)) + (wv ? xq0.y : xq0.x);
      float pX1 = pr1 + fmaf(h64v, xka1, fmaf(h65v, xkb1, bx1)) + (wv ? xq1.y : xq1.x);
      float pX2 = pr2 + fmaf(h64v, xka2, fmaf(h65v, xkb2, bx2)) + (wv ? xq0.w : xq0.z);
      float pX3 = pr3 + fmaf(h64v, xka3, fmaf(h65v, xkb3, bx3)) + (wv ? xq1.w : xq1.z);

      sMa[par][wv][l] = accU;
      sMb[par][wv][l] = accV;
      if (l == 0) {
        float4 t4 = make_float4(pX0, pX1, pX2, pX3);
        *(float4*)&sX[par][wv][0] = t4;
      }
      __syncthreads();  // the ONLY barrier per step

      float oU = sMa[par][1 - wv][l];
      float oV = sMb[par][1 - wv][l];
      float4 oX = *(const float4*)&sX[par][1 - wv][0];
      // Own cell l (both waves redundantly):
      float pi = wv ? oU : accU;
      float pf = wv ? accU : oU;
      float pg = wv ? oV : accV;
      float po = wv ? accV : oV;
      float iv = fast_sigmoid(pi), fv = fast_sigmoid(pf);
      float gv = fast_tanh(pg), ov = fast_sigmoid(po);
      c_ = fmaf(fv, c_, iv * gv);
      h_ = ov * fast_tanh(c_);
      // Cells 64,65 (wave-uniform, both waves redundantly):
      float pi64 = wv ? oX.x : pX0, pi65 = wv ? oX.y : pX1;
      float pg64 = wv ? oX.z : pX2, pg65 = wv ? oX.w : pX3;
      float pf64 = wv ? pX0 : oX.x, pf65 = wv ? pX1 : oX.y;
      float po64 = wv ? pX2 : oX.z, po65 = wv ? pX3 : oX.w;
      c64 = fmaf(fast_sigmoid(pf64), c64, fast_sigmoid(pi64) * fast_tanh(pg64));
      h64v = fast_sigmoid(po64) * fast_tanh(c64);
      c65 = fmaf(fast_sigmoid(pf65), c65, fast_sigmoid(pi65) * fast_tanh(pg65));
      h65v = fast_sigmoid(po65) * fast_tanh(c65);
    }
  }
  if (tid < 64) hT[tid * BB + b] = h_;   // wave 0, lane l holds h[l]
  if (tid == 0) {
    hT[64 * BB + b] = h64v;
    hT[65 * BB + b] = h65v;
  }
}

// BN batch-stats folded into final linear. Single block.
__global__ __launch_bounds__(512) void bn_fc(
    const float* __restrict__ hT, const float* __restrict__ gamma,
    const float* __restrict__ beta, const float* __restrict__ fc_w,
    const float* __restrict__ fc_b, float* __restrict__ out) {
  __shared__ float w2[HH];
  __shared__ float s2[HH];
  const int tid = threadIdx.x;
  const int wvv = tid >> 6;
  const int lane = tid & 63;

  for (int j = wvv; j < HH; j += 8) {
    const float* p = hT + j * BB;
    float s = 0.0f, ss = 0.0f;
#pragma unroll
    for (int m = 0; m < 8; ++m) {
      float v = p[lane + (m << 6)];
      s += v;
      ss = fmaf(v, v, ss);
    }
#pragma unroll
    for (int d = 32; d >= 1; d >>= 1) {
      s += __shfl_xor(s, d);
      ss += __shfl_xor(ss, d);
    }
    if (lane == 0) {
      float mean = s * (1.0f / BB);
      float var = ss * (1.0f / BB) - mean * mean;
      float scale = gamma[j] * rsqrtf(var + 1e-5f);
      float shift = beta[j] - mean * scale;
      float fw = fc_w[j];
      w2[j] = scale * fw;
      s2[j] = shift * fw;
    }
  }
  __syncthreads();

  float acc = 0.0f;
#pragma unroll
  for (int j = 0; j < HH; ++j) acc = fmaf(hT[j * BB + tid], w2[j], acc);
  float cst = fc_b[0];
#pragma unroll
  for (int j = 0; j < HH; ++j) cst += s2[j];
  out[tid] = acc + cst;
}

extern "C" void kernel_launch(void* const* d_in, const int* in_sizes, int n_in,
                              void* d_out, int out_size, void* d_ws, size_t ws_size,
                              hipStream_t stream) {
  const float* x     = (const float*)d_in[0];
  const float* W_ih  = (const float*)d_in[1];
  const float* W_hh  = (const float*)d_in[2];
  const float* b_ih  = (const float*)d_in[3];
  const float* b_hh  = (const float*)d_in[4];
  const float* gamma = (const float*)d_in[5];
  const float* beta  = (const float*)d_in[6];
  const float* fc_w  = (const float*)d_in[7];
  const float* fc_b  = (const float*)d_in[8];
  float* out = (float*)d_out;

  unsigned short* wbhi = (unsigned short*)d_ws;                  // 34816 B
  unsigned short* wblo = (unsigned short*)((char*)d_ws + 34816); // 34816 B
  float* hT            = (float*)((char*)d_ws + 69632);          // 135168 B

  conv_w<<<68, 256, 0, stream>>>(W_ih, wbhi, wblo);
  lstm_two<<<BB, 128, 0, stream>>>(x, W_hh, b_ih, b_hh, wbhi, wblo, hT);
  bn_fc<<<1, 512, 0, stream>>>(hT, gamma, beta, fc_w, fc_b, out);
}